// Round 11
// baseline (395.835 us; speedup 1.0000x reference)
//
#include <hip/hip_runtime.h>
#include <hip/hip_bf16.h>
#include <cstdint>

#define DD 8192
#define NROW 200
#define MT 13          // 13 M-tiles of 16 rows = 208
#define MPAD 208
#define KPV 256        // padded K for the PV GEMM
#define EPSV 1e-5f
#define BK 64

using short8 = __attribute__((ext_vector_type(8))) short;
using f32x4  = __attribute__((ext_vector_type(4))) float;

#define MEMBAR asm volatile("" ::: "memory")

__device__ __forceinline__ ushort f2bf(float f) {
    union { float f; unsigned u; } c; c.f = f;
    unsigned u = c.u;
    return (ushort)((u + 0x7FFFu + ((u >> 16) & 1u)) >> 16);  // RNE
}

__device__ __forceinline__ short8 pack8v(f32x4 a, f32x4 b) {
    short8 o;
    o[0]=f2bf(a[0]); o[1]=f2bf(a[1]); o[2]=f2bf(a[2]); o[3]=f2bf(a[3]);
    o[4]=f2bf(b[0]); o[5]=f2bf(b[1]); o[6]=f2bf(b[2]); o[7]=f2bf(b[3]);
    return o;
}

// ---------------- kernel 1: x (f32 [200][8192]) -> xb (bf16 [208][8192], pad rows 0)
// nt loads: x is read-once, keep it out of the way of L2.
__global__ void cvt_x(const float* __restrict__ x, ushort* __restrict__ xb) {
    int i = (blockIdx.x * 256 + threadIdx.x) * 8;
    int row = i >> 13;
    int col = i & (DD - 1);
    short8 o;
    if (row < NROW) {
        const f32x4* p = reinterpret_cast<const f32x4*>(x + (size_t)row * DD + col);
        f32x4 a = __builtin_nontemporal_load(p);
        f32x4 b = __builtin_nontemporal_load(p + 1);
        o = pack8v(a, b);
    } else {
        for (int j = 0; j < 8; ++j) o[j] = 0;
    }
    *reinterpret_cast<short8*>(xb + i) = o;
}

// ---------------- kernel 2: fused QKV GEMM — M-split waves, W via 4KB LDS dbuf,
// A register-prefetched 1 phase ahead, W NON-TEMPORAL (nt) so the streaming W
// traffic does not evict xb (3.4 MB) from each XCD's 4 MB L2. A-loads then hit L2
// instead of L3 — removes the L3 delivery wall measured in R10.
// grid 768 = 3 mats x 256 colblocks, block 256 (4 waves). Block: 32 N-cols, all 208
// rows, full K, no partials. Wave w owns M-tiles {w, w+4, w+8, w+12} (<13).
// One lgkmcnt(0)+s_barrier per phase. 3 blocks/CU = 12 waves/CU.
__global__ __launch_bounds__(256) void qkv_dir3(
    const ushort* __restrict__ xb,
    const float* __restrict__ Wq, const float* __restrict__ Wk, const float* __restrict__ Wv,
    const float* __restrict__ bq, const float* __restrict__ bk, const float* __restrict__ bv,
    ushort* __restrict__ qb, ushort* __restrict__ kb, ushort* __restrict__ vt)
{
    __shared__ char Wl[2][4096];   // [buf][32 cols][8 swizzled 16B k-slots]

    const int bid = blockIdx.x;
    const int mat = bid >> 8;          // 0..2
    const int cb  = bid & 255;         // col-block (32 cols)
    const float* W    = (mat == 0) ? Wq : (mat == 1 ? Wk : Wv);
    const float* bias = (mat == 0) ? bq : (mat == 1 ? bk : bv);

    const int t    = threadIdx.x;
    const int lane = t & 63;
    const int wave = t >> 6;
    const int c    = lane & 15;
    const int kgrp = lane >> 4;
    const int ncol0 = cb * 32 + c;
    const int ncol1 = ncol0 + 16;

    // W coop staging: thread t -> col t>>3 (0..31), k-slot t&7 (8 fp32 each)
    const float* wsrc = W + (size_t)(cb * 32 + (t >> 3)) * DD + (t & 7) * 8;
    const int wbyte = (t >> 3) * 128 + (((t & 7) ^ ((t >> 3) & 7)) * 16);

    // b-frag reads: col c, chunk j slot = (j*4+kgrp) ^ (c&7); cg1 adds 2048
    const int rb0 = c * 128 + (((kgrp)     ^ (c & 7)) * 16);
    const int rb1 = c * 128 + (((4 + kgrp) ^ (c & 7)) * 16);

    // A fragment base pointers (per M-tile), direct from global (xb L2-resident)
    const int mt0 = wave, mt1 = wave + 4, mt2 = wave + 8, mt3 = wave + 12;
    const ushort* a0p = xb + (size_t)(mt0 * 16 + c) * DD + kgrp * 8;
    const ushort* a1p = xb + (size_t)(mt1 * 16 + c) * DD + kgrp * 8;
    const ushort* a2p = xb + (size_t)(mt2 * 16 + c) * DD + kgrp * 8;
    const ushort* a3p = xb + (size_t)(mt3 * 16 + c) * DD + kgrp * 8;   // wave0 only
    const bool has3 = (mt3 < MT);

    f32x4 acc00, acc01, acc10, acc11, acc20, acc21, acc30, acc31;
    for (int r = 0; r < 4; ++r) {
        acc00[r]=0.f; acc01[r]=0.f; acc10[r]=0.f; acc11[r]=0.f;
        acc20[r]=0.f; acc21[r]=0.f; acc30[r]=0.f; acc31[r]=0.f;
    }

    // two named A-prefetch sets (static indexing only — rule #20)
    short8 aE0, aE1, aE2, aE3, aE4, aE5, aE6, aE7;
    short8 aO0, aO1, aO2, aO3, aO4, aO5, aO6, aO7;
    f32x4 wa0, wa1, wb0, wb1;

#define ALOADM(S, KK) { \
        S##0 = *reinterpret_cast<const short8*>(a0p + (KK)); \
        S##1 = *reinterpret_cast<const short8*>(a0p + (KK) + 32); \
        S##2 = *reinterpret_cast<const short8*>(a1p + (KK)); \
        S##3 = *reinterpret_cast<const short8*>(a1p + (KK) + 32); \
        S##4 = *reinterpret_cast<const short8*>(a2p + (KK)); \
        S##5 = *reinterpret_cast<const short8*>(a2p + (KK) + 32); \
        if (has3) { \
            S##6 = *reinterpret_cast<const short8*>(a3p + (KK)); \
            S##7 = *reinterpret_cast<const short8*>(a3p + (KK) + 32); } }

#define LOADWREG(d, KK) { \
        d##0 = __builtin_nontemporal_load(reinterpret_cast<const f32x4*>(wsrc + (KK))); \
        d##1 = __builtin_nontemporal_load(reinterpret_cast<const f32x4*>(wsrc + (KK) + 4)); }

#define PHASE(BUF, K0, AU, AL, WF, WW) { \
        /* issue A(p+1) into the other set (consumed next phase) */ \
        ALOADM(AL, ((K0) + BK) & (DD - 1)); \
        MEMBAR; \
        /* issue W(p+2) global (nt) into freed regs */ \
        LOADWREG(WF, ((K0) + 2 * BK) & (DD - 1)); \
        MEMBAR; \
        /* write W(p+1) (regs loaded 2 phases ago) into other LDS buffer */ \
        *reinterpret_cast<short8*>(&Wl[(BUF) ^ 1][wbyte]) = pack8v(WW##0, WW##1); \
        /* b-frags for THIS phase from Wl[BUF] */ \
        short8 b00 = *reinterpret_cast<const short8*>(&Wl[BUF][rb0]); \
        short8 b01 = *reinterpret_cast<const short8*>(&Wl[BUF][rb1]); \
        short8 b10 = *reinterpret_cast<const short8*>(&Wl[BUF][2048 + rb0]); \
        short8 b11 = *reinterpret_cast<const short8*>(&Wl[BUF][2048 + rb1]); \
        /* MFMAs on registers prefetched last phase */ \
        acc00 = __builtin_amdgcn_mfma_f32_16x16x32_bf16(AU##0, b00, acc00, 0, 0, 0); \
        acc01 = __builtin_amdgcn_mfma_f32_16x16x32_bf16(AU##0, b10, acc01, 0, 0, 0); \
        acc00 = __builtin_amdgcn_mfma_f32_16x16x32_bf16(AU##1, b01, acc00, 0, 0, 0); \
        acc01 = __builtin_amdgcn_mfma_f32_16x16x32_bf16(AU##1, b11, acc01, 0, 0, 0); \
        acc10 = __builtin_amdgcn_mfma_f32_16x16x32_bf16(AU##2, b00, acc10, 0, 0, 0); \
        acc11 = __builtin_amdgcn_mfma_f32_16x16x32_bf16(AU##2, b10, acc11, 0, 0, 0); \
        acc10 = __builtin_amdgcn_mfma_f32_16x16x32_bf16(AU##3, b01, acc10, 0, 0, 0); \
        acc11 = __builtin_amdgcn_mfma_f32_16x16x32_bf16(AU##3, b11, acc11, 0, 0, 0); \
        acc20 = __builtin_amdgcn_mfma_f32_16x16x32_bf16(AU##4, b00, acc20, 0, 0, 0); \
        acc21 = __builtin_amdgcn_mfma_f32_16x16x32_bf16(AU##4, b10, acc21, 0, 0, 0); \
        acc20 = __builtin_amdgcn_mfma_f32_16x16x32_bf16(AU##5, b01, acc20, 0, 0, 0); \
        acc21 = __builtin_amdgcn_mfma_f32_16x16x32_bf16(AU##5, b11, acc21, 0, 0, 0); \
        if (has3) { \
            acc30 = __builtin_amdgcn_mfma_f32_16x16x32_bf16(AU##6, b00, acc30, 0, 0, 0); \
            acc31 = __builtin_amdgcn_mfma_f32_16x16x32_bf16(AU##6, b10, acc31, 0, 0, 0); \
            acc30 = __builtin_amdgcn_mfma_f32_16x16x32_bf16(AU##7, b01, acc30, 0, 0, 0); \
            acc31 = __builtin_amdgcn_mfma_f32_16x16x32_bf16(AU##7, b11, acc31, 0, 0, 0); \
        } \
        asm volatile("s_waitcnt lgkmcnt(0)" ::: "memory"); \
        asm volatile("s_barrier" ::: "memory"); }

    // ---------------- prologue: A(0)->aE; wa=W(0); wb=W(1); W(0)->buf0
    ALOADM(aE, 0);
    MEMBAR;
    LOADWREG(wa, 0);
    MEMBAR;
    LOADWREG(wb, BK);
    MEMBAR;
    *reinterpret_cast<short8*>(&Wl[0][wbyte]) = pack8v(wa0, wa1);   // waits wa
    asm volatile("s_waitcnt lgkmcnt(0)" ::: "memory");
    asm volatile("s_barrier" ::: "memory");

    int k0 = 0;
    #pragma unroll 1
    for (int it = 0; it < DD / (2 * BK); ++it) {
        // even phase p: consume aE + buf0; load A(p+1)->aO, W(p+2)->wa; write W(p+1)=wb->buf1
        PHASE(0, k0, aE, aO, wa, wb);
        // odd phase p+1: consume aO + buf1; load A(p+2)->aE, W(p+3)->wb; write W(p+2)=wa->buf0
        PHASE(1, k0 + BK, aO, aE, wb, wa);
        k0 += 2 * BK;
    }
#undef PHASE
#undef ALOADM
#undef LOADWREG

    // ---------------- epilogue: direct stores (no partials)
    const float b0v = bias[ncol0];
    const float b1v = bias[ncol1];
#define STORE_TILE(MTV, A0, A1) { \
        if ((MTV) < MT) { \
            if (mat < 2) { \
                ushort* outb = (mat == 0) ? qb : kb; \
                _Pragma("unroll") for (int r = 0; r < 4; ++r) { \
                    int row = (MTV) * 16 + kgrp * 4 + r; \
                    outb[(size_t)row * DD + ncol0] = f2bf(A0[r] + b0v); \
                    outb[(size_t)row * DD + ncol1] = f2bf(A1[r] + b1v); \
                } \
            } else { \
                _Pragma("unroll") for (int r = 0; r < 4; ++r) { \
                    int row = (MTV) * 16 + kgrp * 4 + r; \
                    vt[(size_t)ncol0 * KPV + row] = f2bf(A0[r] + b0v); \
                    vt[(size_t)ncol1 * KPV + row] = f2bf(A1[r] + b1v); \
                } \
            } \
        } }
    STORE_TILE(mt0, acc00, acc01);
    STORE_TILE(mt1, acc10, acc11);
    STORE_TILE(mt2, acc20, acc21);
    STORE_TILE(mt3, acc30, acc31);
#undef STORE_TILE
}

// ---------------- kernel 4: s = q @ k^T  (f32 [208][208]); grid (13,13), 4-wave K-split
__global__ __launch_bounds__(256) void sgemm(const ushort* __restrict__ qb, const ushort* __restrict__ kb,
                                             float* __restrict__ sbuf) {
    const int bm = blockIdx.y, bn = blockIdx.x;
    const int lane  = threadIdx.x & 63;
    const int wave  = threadIdx.x >> 6;
    const int col16 = lane & 15, kgrp = lane >> 4;
    const ushort* ap = qb + (size_t)(bm * 16 + col16) * DD + kgrp * 8;
    const ushort* bp = kb + (size_t)(bn * 16 + col16) * DD + kgrp * 8;
    f32x4 acc;
    for (int r = 0; r < 4; ++r) acc[r] = 0.f;
    const int kend = (wave + 1) * 2048;
    for (int k0 = wave * 2048; k0 < kend; k0 += 32) {
        short8 a = *reinterpret_cast<const short8*>(ap + k0);
        short8 b = *reinterpret_cast<const short8*>(bp + k0);
        acc = __builtin_amdgcn_mfma_f32_16x16x32_bf16(a, b, acc, 0, 0, 0);
    }
    __shared__ f32x4 red[4][64];
    red[wave][lane] = acc;
    __syncthreads();
    if (wave == 0) {
        f32x4 s = red[0][lane];
        for (int j = 1; j < 4; ++j) { f32x4 o = red[j][lane]; for (int r = 0; r < 4; ++r) s[r] += o[r]; }
        for (int r = 0; r < 4; ++r)
            sbuf[(size_t)(bm * 16 + kgrp * 4 + r) * MPAD + bn * 16 + col16] = s[r];
    }
}

// ---------------- kernel 5: per-row mean/var(ddof=1) -> sin -> softmax -> P bf16 [208][256] (pads 0)
__global__ __launch_bounds__(256) void rownorm(const float* __restrict__ sbuf, ushort* __restrict__ pb) {
    const int row = blockIdx.x;
    const int t = threadIdx.x;
    if (row >= NROW) { pb[(size_t)row * KPV + t] = 0; return; }
    __shared__ float part[4];
    const int lane = t & 63, wave = t >> 6;
    float x = (t < NROW) ? sbuf[(size_t)row * MPAD + t] : 0.f;

    float s = x;
    for (int m = 32; m; m >>= 1) s += __shfl_xor(s, m, 64);
    if (lane == 0) part[wave] = s;
    __syncthreads();
    float mean = (part[0] + part[1] + part[2] + part[3]) * (1.f / 200.f);

    float d = (t < NROW) ? (x - mean) : 0.f;
    float s2 = d * d;
    for (int m = 32; m; m >>= 1) s2 += __shfl_xor(s2, m, 64);
    __syncthreads();
    if (lane == 0) part[wave] = s2;
    __syncthreads();
    float var = (part[0] + part[1] + part[2] + part[3]) * (1.f / 199.f);

    float inv = 1.f / sqrtf(var + EPSV);
    float y = sinf(d * inv);
    const float inv_cc = 1.f / 90.50966799187809f;   // 1/sqrt(8192)
    float e = (t < NROW) ? expf(y * inv_cc) : 0.f;

    float se = e;
    for (int m = 32; m; m >>= 1) se += __shfl_xor(se, m, 64);
    __syncthreads();
    if (lane == 0) part[wave] = se;
    __syncthreads();
    float tot = part[0] + part[1] + part[2] + part[3];
    pb[(size_t)row * KPV + t] = (t < NROW) ? f2bf(e / tot) : (ushort)0;
}

// ---------------- kernel 6: out = P @ V  via out[m][n] = sum_k P[m][k] * vt[n][k]
__global__ __launch_bounds__(256) void pv_gemm(const ushort* __restrict__ pb, const ushort* __restrict__ vt,
                                               float* __restrict__ out) {
    const int lane  = threadIdx.x & 63;
    const int wave  = threadIdx.x >> 6;
    const int col16 = lane & 15, kgrp = lane >> 4;
    const int ncol  = blockIdx.x * 64 + wave * 16 + col16;
    const ushort* ap = pb + (size_t)col16 * KPV + kgrp * 8;
    const ushort* bp = vt + (size_t)ncol  * KPV + kgrp * 8;
    f32x4 acc[MT];
    for (int m = 0; m < MT; ++m)
        for (int r = 0; r < 4; ++r) acc[m][r] = 0.f;
    for (int k0 = 0; k0 < KPV; k0 += 32) {
        short8 b = *reinterpret_cast<const short8*>(bp + k0);
        #pragma unroll
        for (int m = 0; m < MT; ++m) {
            short8 a = *reinterpret_cast<const short8*>(ap + (size_t)m * 16 * KPV + k0);
            acc[m] = __builtin_amdgcn_mfma_f32_16x16x32_bf16(a, b, acc[m], 0, 0, 0);
        }
    }
    for (int m = 0; m < MT; ++m)
        for (int r = 0; r < 4; ++r) {
            int row = m * 16 + kgrp * 4 + r;
            if (row < NROW) out[(size_t)row * DD + ncol] = acc[m][r];
        }
}

extern "C" void kernel_launch(void* const* d_in, const int* in_sizes, int n_in,
                              void* d_out, int out_size, void* d_ws, size_t ws_size,
                              hipStream_t stream) {
    const float* x  = (const float*)d_in[0];
    const float* Wq = (const float*)d_in[1];
    const float* bq = (const float*)d_in[2];
    const float* Wk = (const float*)d_in[3];
    const float* bk = (const float*)d_in[4];
    const float* Wv = (const float*)d_in[5];
    const float* bv = (const float*)d_in[6];
    float* out = (float*)d_out;

    char* ws = (char*)d_ws;
    ushort* xb   = (ushort*)(ws);                       // 208*8192*2 = 3,407,872
    ushort* qb   = (ushort*)(ws + 3407872);             // 3,407,872
    ushort* kb   = (ushort*)(ws + 6815744);             // 3,407,872
    ushort* vt   = (ushort*)(ws + 10223616);            // 8192*256*2 = 4,194,304
    float*  sbuf = (float*)(ws + 14417920);             // 208*208*4 = 173,056
    ushort* pb   = (ushort*)(ws + 14590976);            // 208*256*2 = 106,496
    // total 14,697,472 bytes

    cvt_x<<<832, 256, 0, stream>>>(x, xb);
    qkv_dir3<<<768, 256, 0, stream>>>(xb, Wq, Wk, Wv, bq, bk, bv, qb, kb, vt);
    sgemm<<<dim3(13, 13), 256, 0, stream>>>(qb, kb, sbuf);
    rownorm<<<208, 256, 0, stream>>>(sbuf, pb);
    pv_gemm<<<128, 256, 0, stream>>>(pb, vt, out);
}